// Round 1
// baseline (21838.997 us; speedup 1.0000x reference)
//
#include <hip/hip_runtime.h>
#include <hip/hip_bf16.h>
#include <math.h>

#define SLEN 4096
#define LCH 24
#define EMB 300
#define CHE 25
#define CHO 25
#define XIN 325      // EMB + CHO
#define HID 512
#define GDIM 2048    // 4*HID
#define NTAG 11
#define TAG_START 9
#define TAG_STOP 10
#define NEGV (-10000.0f)
#define NW 32        // workgroups per LSTM direction

// ---- ws layout (float units) ----
#define WT_F_O   0u
#define WT_B_O   (WT_F_O + XIN*GDIM)          // 665600
#define CF_O     (WT_B_O + XIN*GDIM)          // char_feat [S][25]
#define GF_O     (CF_O + SLEN*CHO)            // G forward [S][2048]
#define GB_O     (GF_O + SLEN*GDIM)
#define HSF_O    (GB_O + SLEN*GDIM)           // hs forward [S][512]
#define HSB_O    (HSF_O + SLEN*HID)
#define FEATS_O  (HSB_O + SLEN*HID)           // feats [S][11]
#define FLAGS_O  (FEATS_O + SLEN*NTAG)        // u32 flags [2][S][NW]
#define FLAGS_N  (2*SLEN*NW)

__device__ __forceinline__ float sigm(float x) { return 1.0f / (1.0f + expf(-x)); }

// ---------------- zero the barrier flags (ws is poisoned each launch) --------
__global__ void k_zero(unsigned* f, int n) {
    int i = blockIdx.x * blockDim.x + threadIdx.x;
    if (i < n) f[i] = 0u;
}

// ---------------- transpose Wih [2048][325] -> Wt [325][2048] ----------------
__global__ void k_transpose(const float* __restrict__ wf, const float* __restrict__ wb,
                            float* __restrict__ ws) {
    int i = blockIdx.x * 256 + threadIdx.x;
    const int per = XIN * GDIM;
    if (i >= 2 * per) return;
    const float* src = (i < per) ? wf : wb;
    float* dst = ws + ((i < per) ? WT_F_O : WT_B_O);
    int r = (i < per) ? i : (i - per);
    int k = r / GDIM, j = r % GDIM;
    dst[r] = src[j * XIN + k];   // writes coalesced, reads strided (L2-cached)
}

// ---------------- char CNN + global max pool ---------------------------------
__global__ __launch_bounds__(64) void k_charcnn(const int* __restrict__ chars,
        const float* __restrict__ cemb, const float* __restrict__ cw,
        const float* __restrict__ cb, float* __restrict__ ws) {
    int s = blockIdx.x, tid = threadIdx.x;
    __shared__ int ch[LCH];
    __shared__ float ce[LCH][CHE];
    if (tid < LCH) ch[tid] = chars[s * LCH + tid];
    __syncthreads();
    for (int idx = tid; idx < LCH * CHE; idx += 64) {
        int l = idx / CHE, e = idx % CHE;
        ce[l][e] = cemb[ch[l] * CHE + e];
    }
    __syncthreads();
    if (tid < CHO) {
        float best = -1e30f;
        for (int h = 0; h < LCH + 2; ++h) {      // 26 output positions (pad=2)
            float acc = cb[tid];
            #pragma unroll
            for (int kh = 0; kh < 3; ++kh) {
                int l = h - 2 + kh;
                if (l >= 0 && l < LCH) {
                    const float* wp = cw + tid * 75 + kh * CHE;
                    #pragma unroll
                    for (int e = 0; e < CHE; ++e) acc += ce[l][e] * wp[e];
                }
            }
            best = fmaxf(best, acc);
        }
        (ws + CF_O)[s * CHO + tid] = best;
    }
}

// ---------------- input projection: G[s][j] = x[s]·Wih[j] + bih[j]+bhh[j] ----
// tile: 32 rows x 256 cols, 256 threads, acc 4x8 per thread
__global__ __launch_bounds__(256) void k_ingemm(const int* __restrict__ sent,
        const float* __restrict__ wemb,
        const float* __restrict__ bih_f, const float* __restrict__ bhh_f,
        const float* __restrict__ bih_b, const float* __restrict__ bhh_b,
        float* __restrict__ ws) {
    const int rt = blockIdx.x, jt = blockIdx.y, dir = blockIdx.z;
    const float* wt = ws + (dir ? WT_B_O : WT_F_O);
    const float* cf = ws + CF_O;
    float* g = ws + (dir ? GB_O : GF_O);
    const float* bih = dir ? bih_b : bih_f;
    const float* bhh = dir ? bhh_b : bhh_f;
    __shared__ float xt[XIN][32];   // transposed x tile (broadcast-friendly reads)
    __shared__ int sl[32];
    const int tid = threadIdx.x;
    const int r0 = rt * 32, j0 = jt * 256;
    if (tid < 32) sl[tid] = sent[r0 + tid];
    __syncthreads();
    for (int idx = tid; idx < XIN * 32; idx += 256) {
        int k = idx >> 5, r = idx & 31;
        float v = (k < EMB) ? wemb[(size_t)sl[r] * EMB + k]
                            : cf[(size_t)(r0 + r) * CHO + (k - EMB)];
        xt[k][r] = v;
    }
    __syncthreads();
    const int jg = tid & 31, rg = tid >> 5;
    const int jb = j0 + jg * 8, rb = rg * 4;
    float acc[4][8];
    #pragma unroll
    for (int a = 0; a < 4; ++a)
        #pragma unroll
        for (int b = 0; b < 8; ++b) acc[a][b] = 0.f;
    for (int k = 0; k < XIN; ++k) {
        float4 xv = *(const float4*)&xt[k][rb];
        const float4* wp = (const float4*)(wt + (size_t)k * GDIM + jb);
        float4 w0 = wp[0], w1 = wp[1];
        float xr[4] = {xv.x, xv.y, xv.z, xv.w};
        float wv[8] = {w0.x, w0.y, w0.z, w0.w, w1.x, w1.y, w1.z, w1.w};
        #pragma unroll
        for (int a = 0; a < 4; ++a)
            #pragma unroll
            for (int b = 0; b < 8; ++b) acc[a][b] += xr[a] * wv[b];
    }
    float bs[8];
    #pragma unroll
    for (int b = 0; b < 8; ++b) bs[b] = bih[jb + b] + bhh[jb + b];
    #pragma unroll
    for (int a = 0; a < 4; ++a) {
        float* gp = g + (size_t)(r0 + rb + a) * GDIM + jb;
        #pragma unroll
        for (int b = 0; b < 8; ++b) gp[b] = acc[a][b] + bs[b];
    }
}

// ---------------- BiLSTM recurrence: 64 WGs (32/dir), Whh slice in VGPRs -----
// WG w owns h[16w..16w+16); 64 gate rows = {i,f,g,o} x 16; 4 threads/row.
__global__ __launch_bounds__(256, 1) void k_lstm(const float* __restrict__ whh_f,
        const float* __restrict__ whh_b, float* __restrict__ ws) {
    const int wg = blockIdx.x;
    const int dir = wg >> 5;
    const int w = wg & 31;
    const int tid = threadIdx.x;
    const int r = tid >> 2;        // local gate row 0..63
    const int part = tid & 3;      // 128-col slice within row
    const int q = r >> 4;          // gate type: 0=i 1=f 2=g 3=o
    const int hj = r & 15;
    const int hbase = w * 16;
    const int grow = q * HID + hbase + hj;   // global gate row
    const float* whh = dir ? whh_b : whh_f;
    const float* gin_p = ws + (dir ? GB_O : GF_O);
    float* hs = ws + (dir ? HSB_O : HSF_O);
    unsigned* flags = (unsigned*)(ws + FLAGS_O) + (size_t)dir * SLEN * NW;

    float4 W[32];
    const float4* wsrc = (const float4*)(whh + (size_t)grow * HID + part * 128);
    #pragma unroll
    for (int i = 0; i < 32; ++i) W[i] = wsrc[i];

    __shared__ float h_lds[HID];
    __shared__ float gates[64];
    __shared__ float cbuf[16];
    for (int idx = tid; idx < HID; idx += 256) h_lds[idx] = 0.f;
    if (tid < 16) cbuf[tid] = 0.f;
    __syncthreads();

    for (int t = 0; t < SLEN; ++t) {
        const int s = dir ? (SLEN - 1 - t) : t;
        float gin = 0.f;
        if (part == 0) gin = gin_p[(size_t)s * GDIM + grow];  // overlaps with dot
        float4 a = {0.f, 0.f, 0.f, 0.f};
        const float4* h4 = (const float4*)(h_lds + part * 128);
        #pragma unroll
        for (int i = 0; i < 32; ++i) {
            float4 h = h4[i];
            a.x += W[i].x * h.x; a.y += W[i].y * h.y;
            a.z += W[i].z * h.z; a.w += W[i].w * h.w;
        }
        float p = (a.x + a.y) + (a.z + a.w);
        p += __shfl_xor(p, 1);
        p += __shfl_xor(p, 2);
        if (part == 0) gates[r] = p + gin;
        __syncthreads();
        if (tid < 16) {
            float gi = gates[tid], gf = gates[16 + tid];
            float gg = gates[32 + tid], go = gates[48 + tid];
            float c = sigm(gf) * cbuf[tid] + sigm(gi) * tanhf(gg);
            cbuf[tid] = c;
            hs[(size_t)s * HID + hbase + tid] = sigm(go) * tanhf(c);
        }
        __syncthreads();   // drains wave0's hs stores (vmcnt 0) before publish
        if (tid == 0) {
            __threadfence();   // agent-scope writeback of hs slice
            __hip_atomic_store(&flags[(size_t)t * NW + w], 1u,
                               __ATOMIC_RELEASE, __HIP_MEMORY_SCOPE_AGENT);
        }
        if (tid < 64) {        // wave 0 polls all 32 flags (one 128B line)
            unsigned f = 1u;
            do {
                if (tid < NW)
                    f = __hip_atomic_load(&flags[(size_t)t * NW + tid],
                                          __ATOMIC_ACQUIRE, __HIP_MEMORY_SCOPE_AGENT);
            } while (__ballot(f != 0u) != ~0ull);
            __threadfence();   // acquire: invalidate L1/L2 before h reload
        }
        __syncthreads();
        if (tid < 128)
            ((float4*)h_lds)[tid] = ((const float4*)(hs + (size_t)s * HID))[tid];
        __syncthreads();
    }
}

// ---------------- feats = [h_f|h_b] @ h2t_w^T + h2t_b ------------------------
__global__ __launch_bounds__(64) void k_feats(const float* __restrict__ h2tw,
        const float* __restrict__ h2tb, float* __restrict__ ws) {
    const int s = blockIdx.x, l = threadIdx.x;
    const float* hf = ws + HSF_O + (size_t)s * HID;
    const float* hb = ws + HSB_O + (size_t)s * HID;
    float xf[8], xb[8];
    #pragma unroll
    for (int m = 0; m < 8; ++m) { xf[m] = hf[l + 64 * m]; xb[m] = hb[l + 64 * m]; }
    float* feats = ws + FEATS_O;
    for (int t = 0; t < NTAG; ++t) {
        const float* wp = h2tw + (size_t)t * (2 * HID);
        float p = 0.f;
        #pragma unroll
        for (int m = 0; m < 8; ++m)
            p += xf[m] * wp[l + 64 * m] + xb[m] * wp[HID + l + 64 * m];
        #pragma unroll
        for (int o = 32; o; o >>= 1) p += __shfl_down(p, o);
        if (l == 0) feats[(size_t)s * NTAG + t] = p + h2tb[t];
    }
}

// ---------------- Viterbi decode (single wave, bptrs in LDS) -----------------
__global__ __launch_bounds__(64) void k_viterbi(const float* __restrict__ trans,
        float* __restrict__ ws, float* __restrict__ out) {
    const int lane = threadIdx.x;
    __shared__ float fbuf[256 * NTAG];          // feats chunk (11 KB)
    __shared__ unsigned char bp[SLEN * NTAG];   // backpointers (44 KB)
    const float* feats = ws + FEATS_O;
    const int li = (lane < NTAG) ? lane : 0;
    float trow[NTAG];
    #pragma unroll
    for (int jj = 0; jj < NTAG; ++jj)
        trow[jj] = (lane < NTAG) ? trans[lane * NTAG + jj] : NEGV;
    float fv = (lane == TAG_START) ? 0.f : NEGV;
    for (int c = 0; c < SLEN / 256; ++c) {
        for (int idx = lane; idx < 256 * NTAG; idx += 64)
            fbuf[idx] = feats[(size_t)c * 256 * NTAG + idx];
        __syncthreads();
        for (int ss = 0; ss < 256; ++ss) {
            const int s = c * 256 + ss;
            float best = -1e30f; int bj = 0;
            #pragma unroll
            for (int jj = 0; jj < NTAG; ++jj) {
                float v = __shfl(fv, jj) + trow[jj];
                if (v > best) { best = v; bj = jj; }   // strict > => first-max
            }
            fv = best + fbuf[ss * NTAG + li];
            if (lane < NTAG) bp[s * NTAG + lane] = (unsigned char)bj;
        }
        __syncthreads();
    }
    float term = fv + ((lane < NTAG) ? trans[TAG_STOP * NTAG + lane] : NEGV);
    if (lane == TAG_START || lane == TAG_STOP) term = NEGV;
    float bestv = -1e30f; int bt = 0;
    #pragma unroll
    for (int jj = 0; jj < NTAG; ++jj) {        // all lanes execute (shfl active)
        float v = __shfl(term, jj);
        if (v > bestv) { bestv = v; bt = jj; }
    }
    unsigned char* path = (unsigned char*)fbuf;  // reuse: 4096 B < 11 KB
    if (lane == 0) {
        int tag = bt;
        for (int s2 = SLEN - 1; s2 >= 0; --s2) {
            path[s2] = (unsigned char)tag;
            tag = bp[s2 * NTAG + tag];
        }
        out[0] = bestv;
    }
    __syncthreads();
    for (int idx = lane; idx < SLEN; idx += 64)
        out[1 + idx] = (float)path[idx];
}

extern "C" void kernel_launch(void* const* d_in, const int* in_sizes, int n_in,
                              void* d_out, int out_size, void* d_ws, size_t ws_size,
                              hipStream_t stream) {
    const int*   sentence = (const int*)  d_in[0];
    const int*   chars    = (const int*)  d_in[1];
    const float* word_emb = (const float*)d_in[4];
    const float* char_emb = (const float*)d_in[5];
    const float* conv_w   = (const float*)d_in[6];
    const float* conv_b   = (const float*)d_in[7];
    const float* Wih_f    = (const float*)d_in[8];
    const float* Whh_f    = (const float*)d_in[9];
    const float* bih_f    = (const float*)d_in[10];
    const float* bhh_f    = (const float*)d_in[11];
    const float* Wih_b    = (const float*)d_in[12];
    const float* Whh_b    = (const float*)d_in[13];
    const float* bih_b    = (const float*)d_in[14];
    const float* bhh_b    = (const float*)d_in[15];
    const float* h2t_w    = (const float*)d_in[16];
    const float* h2t_b    = (const float*)d_in[17];
    const float* trans    = (const float*)d_in[18];
    float* ws  = (float*)d_ws;
    float* out = (float*)d_out;

    unsigned* flags = (unsigned*)(ws + FLAGS_O);
    k_zero<<<(FLAGS_N + 255) / 256, 256, 0, stream>>>(flags, FLAGS_N);
    k_transpose<<<(2 * XIN * GDIM + 255) / 256, 256, 0, stream>>>(Wih_f, Wih_b, ws);
    k_charcnn<<<SLEN, 64, 0, stream>>>(chars, char_emb, conv_w, conv_b, ws);
    k_ingemm<<<dim3(SLEN / 32, GDIM / 256, 2), 256, 0, stream>>>(
        sentence, word_emb, bih_f, bhh_f, bih_b, bhh_b, ws);
    k_lstm<<<2 * NW, 256, 0, stream>>>(Whh_f, Whh_b, ws);
    k_feats<<<SLEN, 64, 0, stream>>>(h2t_w, h2t_b, ws);
    k_viterbi<<<1, 64, 0, stream>>>(trans, ws, out);
}

// Round 4
// 10560.269 us; speedup vs baseline: 2.0680x; 2.0680x over previous
//
#include <hip/hip_runtime.h>
#include <hip/hip_bf16.h>
#include <math.h>

#define SLEN 4096
#define LCH 24
#define EMB 300
#define CHE 25
#define CHO 25
#define XIN 325      // EMB + CHO
#define HID 512
#define GDIM 2048    // 4*HID
#define NTAG 11
#define TAG_START 9
#define TAG_STOP 10
#define NEGV (-10000.0f)
#define NW 32        // workgroups per LSTM direction
#define SENT 0x7FC00000u   // NaN sentinel: h = sigm*tanh can never be NaN

// ---- ws layout (float units) ----
#define WT_F_O   0u
#define WT_B_O   (WT_F_O + XIN*GDIM)          // Wih^T forward/backward
#define CF_O     (WT_B_O + XIN*GDIM)          // char_feat [S][25]
#define GF_O     (CF_O + SLEN*CHO)            // G forward [S][2048]
#define GB_O     (GF_O + SLEN*GDIM)
#define HSF_O    (GB_O + SLEN*GDIM)           // hs forward [S][512]
#define HSB_O    (HSF_O + SLEN*HID)
#define FEATS_O  (HSB_O + SLEN*HID)           // feats [S][11]

__device__ __forceinline__ float sigm(float x) { return 1.0f / (1.0f + expf(-x)); }

// -------- sentinel-fill hs (ws is re-poisoned to 0xAA before every launch) ---
__global__ void k_fill(unsigned* __restrict__ p, int n, unsigned val) {
    int i = blockIdx.x * 256 + threadIdx.x;
    int stride = gridDim.x * 256;
    for (; i < n; i += stride) p[i] = val;
}

// -------- tiled transpose Wih [2048][325] -> Wt [325][2048] ------------------
// grid (ceil(XIN/32), GDIM/32, 2), block (32,8). Coalesced both sides via LDS.
__global__ __launch_bounds__(256) void k_transpose(const float* __restrict__ wf,
        const float* __restrict__ wb, float* __restrict__ ws) {
    __shared__ float tile[32][33];
    const int dir = blockIdx.z;
    const float* src = dir ? wb : wf;                  // [GDIM][XIN]
    float* dst = ws + (dir ? WT_B_O : WT_F_O);         // [XIN][GDIM]
    const int k0 = blockIdx.x * 32, j0 = blockIdx.y * 32;
    const int tx = threadIdx.x, ty = threadIdx.y;
    for (int yy = ty; yy < 32; yy += 8) {
        int k = k0 + tx;
        tile[yy][tx] = (k < XIN) ? src[(size_t)(j0 + yy) * XIN + k] : 0.f;
    }
    __syncthreads();
    for (int yy = ty; yy < 32; yy += 8) {
        int k = k0 + yy;
        if (k < XIN) dst[(size_t)k * GDIM + j0 + tx] = tile[tx][yy];
    }
}

// ---------------- char CNN + global max pool ---------------------------------
__global__ __launch_bounds__(64) void k_charcnn(const int* __restrict__ chars,
        const float* __restrict__ cemb, const float* __restrict__ cw,
        const float* __restrict__ cb, float* __restrict__ ws) {
    int s = blockIdx.x, tid = threadIdx.x;
    __shared__ int ch[LCH];
    __shared__ float ce[LCH][CHE];
    if (tid < LCH) ch[tid] = chars[s * LCH + tid];
    __syncthreads();
    for (int idx = tid; idx < LCH * CHE; idx += 64) {
        int l = idx / CHE, e = idx % CHE;
        ce[l][e] = cemb[ch[l] * CHE + e];
    }
    __syncthreads();
    if (tid < CHO) {
        float best = -1e30f;
        for (int h = 0; h < LCH + 2; ++h) {      // 26 output positions (pad=2)
            float acc = cb[tid];
            #pragma unroll
            for (int kh = 0; kh < 3; ++kh) {
                int l = h - 2 + kh;
                if (l >= 0 && l < LCH) {
                    const float* wp = cw + tid * 75 + kh * CHE;
                    #pragma unroll
                    for (int e = 0; e < CHE; ++e) acc += ce[l][e] * wp[e];
                }
            }
            best = fmaxf(best, acc);
        }
        (ws + CF_O)[s * CHO + tid] = best;
    }
}

// ---------------- input projection: G[s][j] = x[s]·Wih[j] + bih[j]+bhh[j] ----
__global__ __launch_bounds__(256) void k_ingemm(const int* __restrict__ sent,
        const float* __restrict__ wemb,
        const float* __restrict__ bih_f, const float* __restrict__ bhh_f,
        const float* __restrict__ bih_b, const float* __restrict__ bhh_b,
        float* __restrict__ ws) {
    const int rt = blockIdx.x, jt = blockIdx.y, dir = blockIdx.z;
    const float* wt = ws + (dir ? WT_B_O : WT_F_O);
    const float* cf = ws + CF_O;
    float* g = ws + (dir ? GB_O : GF_O);
    const float* bih = dir ? bih_b : bih_f;
    const float* bhh = dir ? bhh_b : bhh_f;
    __shared__ float xt[XIN][32];
    __shared__ int sl[32];
    const int tid = threadIdx.x;
    const int r0 = rt * 32, j0 = jt * 256;
    if (tid < 32) sl[tid] = sent[r0 + tid];
    __syncthreads();
    for (int idx = tid; idx < XIN * 32; idx += 256) {
        int k = idx >> 5, r = idx & 31;
        float v = (k < EMB) ? wemb[(size_t)sl[r] * EMB + k]
                            : cf[(size_t)(r0 + r) * CHO + (k - EMB)];
        xt[k][r] = v;
    }
    __syncthreads();
    const int jg = tid & 31, rg = tid >> 5;
    const int jb = j0 + jg * 8, rb = rg * 4;
    float acc[4][8];
    #pragma unroll
    for (int a = 0; a < 4; ++a)
        #pragma unroll
        for (int b = 0; b < 8; ++b) acc[a][b] = 0.f;
    for (int k = 0; k < XIN; ++k) {
        float4 xv = *(const float4*)&xt[k][rb];
        const float4* wp = (const float4*)(wt + (size_t)k * GDIM + jb);
        float4 w0 = wp[0], w1 = wp[1];
        float xr[4] = {xv.x, xv.y, xv.z, xv.w};
        float wv[8] = {w0.x, w0.y, w0.z, w0.w, w1.x, w1.y, w1.z, w1.w};
        #pragma unroll
        for (int a = 0; a < 4; ++a)
            #pragma unroll
            for (int b = 0; b < 8; ++b) acc[a][b] += xr[a] * wv[b];
    }
    float bs[8];
    #pragma unroll
    for (int b = 0; b < 8; ++b) bs[b] = bih[jb + b] + bhh[jb + b];
    #pragma unroll
    for (int a = 0; a < 4; ++a) {
        float* gp = g + (size_t)(r0 + rb + a) * GDIM + jb;
        #pragma unroll
        for (int b = 0; b < 8; ++b) gp[b] = acc[a][b] + bs[b];
    }
}

// ---------------- BiLSTM recurrence ------------------------------------------
// 64 WGs (32/dir). WG w owns h[16w..16w+16). Thread map: wave = col-part
// (128 cols), lane = gate row (q=lane>>4 in {i,f,g,o}, hj=lane&15).
// LDS dot reads are uniform-address broadcasts (zero bank conflicts).
// Sync: hs prefilled with NaN sentinel; publish = 16 relaxed agent-scope
// atomic stores; readers poll the data words themselves (no fences/flags).
__global__ __launch_bounds__(256, 1) void k_lstm(const float* __restrict__ whh_f,
        const float* __restrict__ whh_b, float* __restrict__ ws) {
    const int wg = blockIdx.x;
    const int dir = wg >> 5;
    const int w = wg & 31;
    const int tid = threadIdx.x;
    const int wave = tid >> 6;      // column part: cols [128*wave, 128*(wave+1))
    const int lane = tid & 63;      // gate row within WG
    const int hbase = w * 16;
    const int q = lane >> 4, hj = lane & 15;
    const int grow = q * HID + hbase + hj;     // global gate row
    const float* whh = dir ? whh_b : whh_f;
    const float* gin_p = ws + (dir ? GB_O : GF_O);
    float* hs = ws + (dir ? HSB_O : HSF_O);

    // Whh slice in VGPRs: W[i] = Whh[grow][wave*128 + 4i ..]
    float4 W[32];
    const float4* wsrc = (const float4*)(whh + (size_t)grow * HID + wave * 128);
    #pragma unroll
    for (int i = 0; i < 32; ++i) W[i] = wsrc[i];

    __shared__ __align__(16) float h_lds[HID];
    __shared__ float part_lds[256];
    for (int i = tid; i < HID; i += 256) h_lds[i] = 0.f;   // h(-1) = 0
    float c = 0.f;                  // cell state lives in lanes tid<16
    __syncthreads();

    int s = dir ? (SLEN - 1) : 0;
    float gin = 0.f;
    if (tid < 64) gin = gin_p[(size_t)s * GDIM + grow];

    for (int t = 0; t < SLEN; ++t) {
        // ---- dot: partial over this wave's 128-col slice (broadcast reads) --
        float4 a = {0.f, 0.f, 0.f, 0.f};
        const float4* h4 = (const float4*)(h_lds + wave * 128);
        #pragma unroll
        for (int i = 0; i < 32; ++i) {
            float4 h = h4[i];
            a.x += W[i].x * h.x; a.y += W[i].y * h.y;
            a.z += W[i].z * h.z; a.w += W[i].w * h.w;
        }
        part_lds[tid] = (a.x + a.y) + (a.z + a.w);
        __syncthreads();

        if (tid < 64) {
            float gsum = part_lds[lane] + part_lds[64 + lane]
                       + part_lds[128 + lane] + part_lds[192 + lane] + gin;
            float gi = __shfl(gsum, hj);
            float gf = __shfl(gsum, 16 + hj);
            float gg = __shfl(gsum, 32 + hj);
            float go = __shfl(gsum, 48 + hj);
            if (lane < 16) {
                c = sigm(gf) * c + sigm(gi) * tanhf(gg);
                float h = sigm(go) * tanhf(c);
                __hip_atomic_store((unsigned*)&hs[(size_t)s * HID + hbase + lane],
                                   __float_as_uint(h),
                                   __ATOMIC_RELAXED, __HIP_MEMORY_SCOPE_AGENT);
            }
        }

        // ---- prefetch next step's G row before the poll spin ----------------
        const int sn = dir ? (s - 1) : (s + 1);
        const int sc = (t + 1 < SLEN) ? sn : s;
        if (tid < 64) gin = gin_p[(size_t)sc * GDIM + grow];

        // ---- poll h(t) directly (data-as-flag): thread owns words 2tid,2tid+1
        const unsigned long long* srcp =
            (const unsigned long long*)(hs + (size_t)s * HID) + tid;
        unsigned long long v;
        do {
            v = __hip_atomic_load(srcp, __ATOMIC_RELAXED, __HIP_MEMORY_SCOPE_AGENT);
        } while ((unsigned)v == SENT || (unsigned)(v >> 32) == SENT);
        ((unsigned long long*)h_lds)[tid] = v;
        __syncthreads();
        s = sc;
    }
}

// ---------------- feats = [h_f|h_b] @ h2t_w^T + h2t_b ------------------------
__global__ __launch_bounds__(64) void k_feats(const float* __restrict__ h2tw,
        const float* __restrict__ h2tb, float* __restrict__ ws) {
    const int s = blockIdx.x, l = threadIdx.x;
    const float* hf = ws + HSF_O + (size_t)s * HID;
    const float* hb = ws + HSB_O + (size_t)s * HID;
    float xf[8], xb[8];
    #pragma unroll
    for (int m = 0; m < 8; ++m) { xf[m] = hf[l + 64 * m]; xb[m] = hb[l + 64 * m]; }
    float* feats = ws + FEATS_O;
    for (int t = 0; t < NTAG; ++t) {
        const float* wp = h2tw + (size_t)t * (2 * HID);
        float p = 0.f;
        #pragma unroll
        for (int m = 0; m < 8; ++m)
            p += xf[m] * wp[l + 64 * m] + xb[m] * wp[HID + l + 64 * m];
        #pragma unroll
        for (int o = 32; o; o >>= 1) p += __shfl_down(p, o);
        if (l == 0) feats[(size_t)s * NTAG + t] = p + h2tb[t];
    }
}

// ---------------- Viterbi decode (single wave, bptrs in LDS) -----------------
__global__ __launch_bounds__(64) void k_viterbi(const float* __restrict__ trans,
        float* __restrict__ ws, float* __restrict__ out) {
    const int lane = threadIdx.x;
    __shared__ float fbuf[256 * NTAG];          // feats chunk (11 KB)
    __shared__ unsigned char bp[SLEN * NTAG];   // backpointers (44 KB)
    const float* feats = ws + FEATS_O;
    const int li = (lane < NTAG) ? lane : 0;
    float trow[NTAG];
    #pragma unroll
    for (int jj = 0; jj < NTAG; ++jj)
        trow[jj] = (lane < NTAG) ? trans[lane * NTAG + jj] : NEGV;
    float fv = (lane == TAG_START) ? 0.f : NEGV;
    for (int ch = 0; ch < SLEN / 256; ++ch) {
        for (int idx = lane; idx < 256 * NTAG; idx += 64)
            fbuf[idx] = feats[(size_t)ch * 256 * NTAG + idx];
        __syncthreads();
        for (int ss = 0; ss < 256; ++ss) {
            const int s = ch * 256 + ss;
            float best = -1e30f; int bj = 0;
            #pragma unroll
            for (int jj = 0; jj < NTAG; ++jj) {
                float v = __shfl(fv, jj) + trow[jj];
                if (v > best) { best = v; bj = jj; }   // strict > => first-max
            }
            fv = best + fbuf[ss * NTAG + li];
            if (lane < NTAG) bp[s * NTAG + lane] = (unsigned char)bj;
        }
        __syncthreads();
    }
    float term = fv + ((lane < NTAG) ? trans[TAG_STOP * NTAG + lane] : NEGV);
    if (lane == TAG_START || lane == TAG_STOP) term = NEGV;
    float bestv = -1e30f; int bt = 0;
    #pragma unroll
    for (int jj = 0; jj < NTAG; ++jj) {
        float v = __shfl(term, jj);
        if (v > bestv) { bestv = v; bt = jj; }
    }
    unsigned char* path = (unsigned char*)fbuf;  // reuse
    if (lane == 0) {
        int tag = bt;
        for (int s2 = SLEN - 1; s2 >= 0; --s2) {
            path[s2] = (unsigned char)tag;
            tag = bp[s2 * NTAG + tag];
        }
        out[0] = bestv;
    }
    __syncthreads();
    for (int idx = lane; idx < SLEN; idx += 64)
        out[1 + idx] = (float)path[idx];
}

extern "C" void kernel_launch(void* const* d_in, const int* in_sizes, int n_in,
                              void* d_out, int out_size, void* d_ws, size_t ws_size,
                              hipStream_t stream) {
    const int*   sentence = (const int*)  d_in[0];
    const int*   chars    = (const int*)  d_in[1];
    const float* word_emb = (const float*)d_in[4];
    const float* char_emb = (const float*)d_in[5];
    const float* conv_w   = (const float*)d_in[6];
    const float* conv_b   = (const float*)d_in[7];
    const float* Wih_f    = (const float*)d_in[8];
    const float* Whh_f    = (const float*)d_in[9];
    const float* bih_f    = (const float*)d_in[10];
    const float* bhh_f    = (const float*)d_in[11];
    const float* Wih_b    = (const float*)d_in[12];
    const float* Whh_b    = (const float*)d_in[13];
    const float* bih_b    = (const float*)d_in[14];
    const float* bhh_b    = (const float*)d_in[15];
    const float* h2t_w    = (const float*)d_in[16];
    const float* h2t_b    = (const float*)d_in[17];
    const float* trans    = (const float*)d_in[18];
    float* ws  = (float*)d_ws;
    float* out = (float*)d_out;

    // NaN-sentinel fill of hs (forward+backward are contiguous at HSF_O)
    k_fill<<<2048, 256, 0, stream>>>((unsigned*)(ws + HSF_O), 2 * SLEN * HID, SENT);
    k_transpose<<<dim3((XIN + 31) / 32, GDIM / 32, 2), dim3(32, 8), 0, stream>>>(
        Wih_f, Wih_b, ws);
    k_charcnn<<<SLEN, 64, 0, stream>>>(chars, char_emb, conv_w, conv_b, ws);
    k_ingemm<<<dim3(SLEN / 32, GDIM / 256, 2), 256, 0, stream>>>(
        sentence, word_emb, bih_f, bhh_f, bih_b, bhh_b, ws);
    k_lstm<<<2 * NW, 256, 0, stream>>>(Whh_f, Whh_b, ws);
    k_feats<<<SLEN, 64, 0, stream>>>(h2t_w, h2t_b, ws);
    k_viterbi<<<1, 64, 0, stream>>>(trans, ws, out);
}